// Round 4
// baseline (2171.958 us; speedup 1.0000x reference)
//
#include <hip/hip_runtime.h>
#include <math.h>

// SentenceDecoder: B=64, D=512, H=1024, V=32000, L=2, T=32. NG = 4H = 4096.
#define BB 64
#define DD 512
#define HH 1024
#define VV 32000
#define NG 4096
#define TT 32
#define KS 8              // K-split for fused gate GEMM
#define VBLK 1000         // V / 32 logits tiles (32-col tiles for occupancy)

typedef __bf16 bf16x8 __attribute__((ext_vector_type(8)));
typedef float  f32x4  __attribute__((ext_vector_type(4)));

// split fp32 into bf16 hi + bf16 lo (RN-even both): x ~= hi + lo, err ~2^-17 rel
__device__ __forceinline__ void split_bf16(float x, unsigned short* hi, unsigned short* lo)
{
    unsigned u = __float_as_uint(x);
    unsigned r = (u + 0x7fffu + ((u >> 16) & 1u)) & 0xffff0000u;
    *hi = (unsigned short)(r >> 16);
    float rem = x - __uint_as_float(r);
    unsigned u2 = __float_as_uint(rem);
    unsigned r2 = u2 + 0x7fffu + ((u2 >> 16) & 1u);
    *lo = (unsigned short)(r2 >> 16);
}

// ---------------------------------------------------------------------------
// split_k: fp32 array -> bf16 hi/lo arrays (one-time per call, weights + feat)
// ---------------------------------------------------------------------------
__global__ __launch_bounds__(256)
void split_k(const float* __restrict__ src, unsigned short* __restrict__ hi,
             unsigned short* __restrict__ lo, int n4)
{
    const int stride = gridDim.x * 256;
    for (int i = blockIdx.x * 256 + threadIdx.x; i < n4; i += stride) {
        const float4 v = ((const float4*)src)[i];
        ushort4 h, l;
        split_bf16(v.x, &h.x, &l.x);
        split_bf16(v.y, &h.y, &l.y);
        split_bf16(v.z, &h.z, &l.z);
        split_bf16(v.w, &h.w, &l.w);
        ((ushort4*)hi)[i] = h;
        ((ushort4*)lo)[i] = l;
    }
}

// ---------------------------------------------------------------------------
// gates_mfma_k: fused dual GEMM via split-bf16 MFMA, register-prefetch
// software pipeline. 64x32 tile (32 N-cols for 4 blocks/CU occupancy),
// 256 thr (4 waves), grid (NG/32, KS) = (128, 8) = 1024 blocks.
//   P[y][b][j] = sum_{k in y-chunk} X[b][k]*Wih[j][k] + H[b][k]*Whh[j][k]
// ---------------------------------------------------------------------------
__global__ __launch_bounds__(256)
void gates_mfma_k(const unsigned short* __restrict__ Ahi0, const unsigned short* __restrict__ Alo0,
                  const int K0,
                  const unsigned short* __restrict__ Ahi1, const unsigned short* __restrict__ Alo1,
                  const unsigned short* __restrict__ Wihhi, const unsigned short* __restrict__ Wihlo,
                  const unsigned short* __restrict__ Whhhi, const unsigned short* __restrict__ Whhlo,
                  float* __restrict__ P)
{
    // stride 72 bf16 = 144 B per row: 16B-aligned, only 2-way bank aliasing
    __shared__ unsigned short Ah[64][72], Al[64][72], Wh[32][72], Wl[32][72];

    const int j0   = blockIdx.x * 32;
    const int y    = blockIdx.y;
    const int tid  = threadIdx.x;
    const int wv   = tid >> 6;        // wave id 0..3 -> m rows 16*wv..
    const int lane = tid & 63;
    const int l15  = lane & 15;
    const int q    = lane >> 4;       // quad 0..3
    const int sr   = tid >> 3;        // staging row 0..31
    const int sc   = tid & 7;         // staging 8-bf16 chunk

    f32x4 acc[2] = {{0,0,0,0},{0,0,0,0}};

    // flat chunk schedule: seg0 (X/Wih, K=K0) then seg1 (H/Whh, K=HH),
    // 64-wide chunks within this block's y-slice of each segment.
    const int n0 = K0 >> 9;           // K0/512 chunks in seg0 (kc0/64)
    const int nc = n0 + (HH >> 9);    // + HH/512 chunks in seg1

    uint4 rA0h, rA0l, rA1h, rA1l, rW0h, rW0l;   // in-flight chunk

#define G_LOAD_CHUNK(cc)                                                        \
    do {                                                                        \
        const int seg_ = ((cc) >= n0);                                          \
        const unsigned short* Ah_ = seg_ ? Ahi1 : Ahi0;                         \
        const unsigned short* Al_ = seg_ ? Alo1 : Alo0;                         \
        const unsigned short* Wh_ = seg_ ? Whhhi : Wihhi;                       \
        const unsigned short* Wl_ = seg_ ? Whhlo : Wihlo;                       \
        const int K_ = seg_ ? HH : K0;                                          \
        const int kb_ = y * (K_ >> 3) + ((cc) - (seg_ ? n0 : 0)) * 64;          \
        const size_t ao_ = (size_t)sr * K_ + kb_ + sc * 8;                      \
        const size_t wo_ = (size_t)(j0 + sr) * K_ + kb_ + sc * 8;               \
        const size_t s32_ = (size_t)32 * K_;                                    \
        rA0h = *(const uint4*)(Ah_ + ao_);                                      \
        rA0l = *(const uint4*)(Al_ + ao_);                                      \
        rA1h = *(const uint4*)(Ah_ + ao_ + s32_);                               \
        rA1l = *(const uint4*)(Al_ + ao_ + s32_);                               \
        rW0h = *(const uint4*)(Wh_ + wo_);                                      \
        rW0l = *(const uint4*)(Wl_ + wo_);                                      \
    } while (0)

    G_LOAD_CHUNK(0);
    for (int c = 0; c < nc; ++c) {
        if (c) __syncthreads();            // prev compute done reading LDS
        *(uint4*)&Ah[sr][sc * 8]      = rA0h;
        *(uint4*)&Al[sr][sc * 8]      = rA0l;
        *(uint4*)&Ah[sr + 32][sc * 8] = rA1h;
        *(uint4*)&Al[sr + 32][sc * 8] = rA1l;
        *(uint4*)&Wh[sr][sc * 8]      = rW0h;
        *(uint4*)&Wl[sr][sc * 8]      = rW0l;
        if (c + 1 < nc) G_LOAD_CHUNK(c + 1);   // issue early: hides under MFMA
        __syncthreads();

#pragma unroll
        for (int ks = 0; ks < 2; ks++) {
            const int ko = ks * 32 + q * 8;
            const bf16x8 ah = *(const bf16x8*)&Ah[16 * wv + l15][ko];
            const bf16x8 al = *(const bf16x8*)&Al[16 * wv + l15][ko];
#pragma unroll
            for (int t = 0; t < 2; t++) {
                const bf16x8 bh = *(const bf16x8*)&Wh[16 * t + l15][ko];
                const bf16x8 bl = *(const bf16x8*)&Wl[16 * t + l15][ko];
                acc[t] = __builtin_amdgcn_mfma_f32_16x16x32_bf16(ah, bl, acc[t], 0, 0, 0);
                acc[t] = __builtin_amdgcn_mfma_f32_16x16x32_bf16(al, bh, acc[t], 0, 0, 0);
                acc[t] = __builtin_amdgcn_mfma_f32_16x16x32_bf16(ah, bh, acc[t], 0, 0, 0);
            }
        }
    }
#undef G_LOAD_CHUNK

    // C/D layout (16x16): col = lane&15, row = q*4 + reg  [m89-verified]
    float* __restrict__ Pout = P + (size_t)y * (BB * NG);
#pragma unroll
    for (int reg = 0; reg < 4; reg++) {
        const int row = 16 * wv + q * 4 + reg;     // batch index
#pragma unroll
        for (int t = 0; t < 2; t++)
            Pout[(size_t)row * NG + j0 + 16 * t + l15] = acc[t][reg];
    }
}

// ---------------------------------------------------------------------------
// cell_k: sum KS partial slices + biases -> gates; LSTM cell; emit bf16 hi/lo
// split of h (the only consumed form of h). c stays fp32.
// ---------------------------------------------------------------------------
__global__ __launch_bounds__(256)
void cell_k(const float* __restrict__ P, const float* __restrict__ bih,
            const float* __restrict__ bhh, float* __restrict__ c,
            unsigned short* __restrict__ hhi, unsigned short* __restrict__ hlo)
{
    const int tid = blockIdx.x * 256 + threadIdx.x;   // B*H threads
    const int b = tid >> 10;
    const int u = tid & (HH - 1);

    float gi = bih[u]          + bhh[u];
    float gf = bih[HH + u]     + bhh[HH + u];
    float gg = bih[2 * HH + u] + bhh[2 * HH + u];
    float go = bih[3 * HH + u] + bhh[3 * HH + u];

#pragma unroll
    for (int s = 0; s < KS; s++) {
        const float* ps = P + (size_t)s * (BB * NG) + (size_t)b * NG;
        gi += ps[u];
        gf += ps[HH + u];
        gg += ps[2 * HH + u];
        go += ps[3 * HH + u];
    }

    const float si = 1.0f / (1.0f + expf(-gi));
    const float sf = 1.0f / (1.0f + expf(-gf));
    const float so = 1.0f / (1.0f + expf(-go));
    const float cn = sf * c[tid] + si * tanhf(gg);
    const float hn = so * tanhf(cn);
    c[tid] = cn;
    split_bf16(hn, &hhi[tid], &hlo[tid]);
}

// ---------------------------------------------------------------------------
// logits_mfma_k: 64x32 logits tile via split-bf16 MFMA with register-prefetch
// software pipeline; argmax-partial epilogue. A (h1) and W (Wout) pre-split.
// Grid: 1000 blocks x 256 thr (4 waves) -> ~4 blocks/CU for latency hiding.
// ---------------------------------------------------------------------------
__global__ __launch_bounds__(256)
void logits_mfma_k(const unsigned short* __restrict__ Ahi,
                   const unsigned short* __restrict__ Alo,
                   const unsigned short* __restrict__ Whi,
                   const unsigned short* __restrict__ Wlo,
                   const float* __restrict__ bout,
                   float* __restrict__ pv, int* __restrict__ pi)
{
    __shared__ unsigned short Ah[64][72], Al[64][72], Wh[32][72], Wl[32][72];
    __shared__ float rv[64][16];
    __shared__ int   ri[64][16];

    const int v0   = blockIdx.x * 32;
    const int tid  = threadIdx.x;
    const int wv   = tid >> 6;
    const int lane = tid & 63;
    const int l15  = lane & 15;
    const int q    = lane >> 4;
    const int sr   = tid >> 3;
    const int sc   = tid & 7;

    f32x4 acc[2] = {{0,0,0,0},{0,0,0,0}};

    uint4 rA0h, rA0l, rA1h, rA1l, rW0h, rW0l;

#define L_LOAD_CHUNK(kb_)                                                       \
    do {                                                                        \
        const size_t ao_ = (size_t)sr * HH + (kb_) + sc * 8;                    \
        const size_t wo_ = (size_t)(v0 + sr) * HH + (kb_) + sc * 8;             \
        const size_t s32_ = (size_t)32 * HH;                                    \
        rA0h = *(const uint4*)(Ahi + ao_);                                      \
        rA0l = *(const uint4*)(Alo + ao_);                                      \
        rA1h = *(const uint4*)(Ahi + ao_ + s32_);                               \
        rA1l = *(const uint4*)(Alo + ao_ + s32_);                               \
        rW0h = *(const uint4*)(Whi + wo_);                                      \
        rW0l = *(const uint4*)(Wlo + wo_);                                      \
    } while (0)

    L_LOAD_CHUNK(0);
    for (int kb = 0; kb < HH; kb += 64) {
        if (kb) __syncthreads();
        *(uint4*)&Ah[sr][sc * 8]      = rA0h;
        *(uint4*)&Al[sr][sc * 8]      = rA0l;
        *(uint4*)&Ah[sr + 32][sc * 8] = rA1h;
        *(uint4*)&Al[sr + 32][sc * 8] = rA1l;
        *(uint4*)&Wh[sr][sc * 8]      = rW0h;
        *(uint4*)&Wl[sr][sc * 8]      = rW0l;
        if (kb + 64 < HH) L_LOAD_CHUNK(kb + 64);   // issue early
        __syncthreads();

#pragma unroll
        for (int ks = 0; ks < 2; ks++) {
            const int ko = ks * 32 + q * 8;
            const bf16x8 ah = *(const bf16x8*)&Ah[16 * wv + l15][ko];
            const bf16x8 al = *(const bf16x8*)&Al[16 * wv + l15][ko];
#pragma unroll
            for (int t = 0; t < 2; t++) {
                const bf16x8 bh = *(const bf16x8*)&Wh[16 * t + l15][ko];
                const bf16x8 bl = *(const bf16x8*)&Wl[16 * t + l15][ko];
                acc[t] = __builtin_amdgcn_mfma_f32_16x16x32_bf16(ah, bl, acc[t], 0, 0, 0);
                acc[t] = __builtin_amdgcn_mfma_f32_16x16x32_bf16(al, bh, acc[t], 0, 0, 0);
                acc[t] = __builtin_amdgcn_mfma_f32_16x16x32_bf16(ah, bh, acc[t], 0, 0, 0);
            }
        }
    }
#undef L_LOAD_CHUNK

    // epilogue: +bias, per-lane argmax over its 2 cols per row, then LDS reduce.
    // C/D layout (16x16): col = lane&15, row = q*4 + reg  [m89-verified]
#pragma unroll
    for (int reg = 0; reg < 4; reg++) {
        float best = -INFINITY;
        int bid = 0x7fffffff;
#pragma unroll
        for (int t = 0; t < 2; t++) {
            const int id = v0 + 16 * t + l15;
            const float v = acc[t][reg] + bout[id];
            if (v > best || (v == best && id < bid)) { best = v; bid = id; }
        }
        rv[16 * wv + q * 4 + reg][l15] = best;
        ri[16 * wv + q * 4 + reg][l15] = bid;
    }
    __syncthreads();

    if (tid < 64) {
        float best = -INFINITY;
        int bid = 0x7fffffff;
        for (int k = 0; k < 16; k++) {
            const float v = rv[tid][k];
            const int id = ri[tid][k];
            if (v > best || (v == best && id < bid)) { best = v; bid = id; }
        }
        pv[(size_t)tid * VBLK + blockIdx.x] = best;
        pi[(size_t)tid * VBLK + blockIdx.x] = bid;
    }
}

// ---------------------------------------------------------------------------
// final_k: reduce VBLK argmax partials per row -> token; gather embed row and
// emit it directly as bf16 hi/lo (the only form the gate kernel consumes).
// ---------------------------------------------------------------------------
__global__ __launch_bounds__(256)
void final_k(const float* __restrict__ pv, const int* __restrict__ pi,
             const float* __restrict__ embed, unsigned short* __restrict__ xhi,
             unsigned short* __restrict__ xlo, int* __restrict__ out, int t)
{
    __shared__ float sv[256];
    __shared__ int   si[256];
    const int b = blockIdx.x;
    const int tid = threadIdx.x;

    float best = -INFINITY;
    int bid = 0x7fffffff;
    for (int k = tid; k < VBLK; k += 256) {
        float v = pv[(size_t)b * VBLK + k];
        int id = pi[(size_t)b * VBLK + k];
        if (v > best || (v == best && id < bid)) { best = v; bid = id; }
    }
    sv[tid] = best; si[tid] = bid;
    __syncthreads();
    for (int s = 128; s > 0; s >>= 1) {
        if (tid < s) {
            float v = sv[tid + s]; int id = si[tid + s];
            if (v > sv[tid] || (v == sv[tid] && id < si[tid])) { sv[tid] = v; si[tid] = id; }
        }
        __syncthreads();
    }
    const int pred = si[0];
    if (tid == 0) out[(size_t)b * TT + t] = pred;
    for (int d = tid; d < DD; d += 256) {
        const float v = embed[(size_t)pred * DD + d];
        split_bf16(v, &xhi[(size_t)b * DD + d], &xlo[(size_t)b * DD + d]);
    }
}

// ---------------------------------------------------------------------------
extern "C" void kernel_launch(void* const* d_in, const int* in_sizes, int n_in,
                              void* d_out, int out_size, void* d_ws, size_t ws_size,
                              hipStream_t stream)
{
    const float* features = (const float*)d_in[0];
    const float* embed    = (const float*)d_in[1];
    const float* Wih0     = (const float*)d_in[2];
    const float* Whh0     = (const float*)d_in[3];
    const float* bih0     = (const float*)d_in[4];
    const float* bhh0     = (const float*)d_in[5];
    const float* Wih1     = (const float*)d_in[6];
    const float* Whh1     = (const float*)d_in[7];
    const float* bih1     = (const float*)d_in[8];
    const float* bhh1     = (const float*)d_in[9];
    const float* Wout     = (const float*)d_in[10];
    const float* bout     = (const float*)d_in[11];
    int* out = (int*)d_out;

    // workspace layout (all offsets 16B-aligned)
    float* ws = (float*)d_ws;
    float* c0 = ws;                                            // B*H fp32
    float* c1 = c0 + BB * HH;
    unsigned short* hhi0 = (unsigned short*)(c1 + BB * HH);    // B*H bf16 each
    unsigned short* hlo0 = hhi0 + BB * HH;
    unsigned short* hhi1 = hlo0 + BB * HH;
    unsigned short* hlo1 = hhi1 + BB * HH;
    unsigned short* xhi  = hlo1 + BB * HH;                     // B*D bf16 each
    unsigned short* xlo  = xhi + BB * DD;
    float* part = (float*)(xlo + BB * DD);                     // KS*B*NG fp32
    float* pv   = part + (size_t)KS * BB * NG;                 // B*VBLK
    int*   pi   = (int*)(pv + BB * VBLK);                      // B*VBLK
    unsigned short* wih0h = (unsigned short*)(pi + BB * VBLK); // NG*D each
    unsigned short* wih0l = wih0h + (size_t)NG * DD;
    unsigned short* whh0h = wih0l + (size_t)NG * DD;           // NG*H each
    unsigned short* whh0l = whh0h + (size_t)NG * HH;
    unsigned short* wih1h = whh0l + (size_t)NG * HH;
    unsigned short* wih1l = wih1h + (size_t)NG * HH;
    unsigned short* whh1h = wih1l + (size_t)NG * HH;
    unsigned short* whh1l = whh1h + (size_t)NG * HH;
    unsigned short* wouth = whh1l + (size_t)NG * HH;           // V*H each
    unsigned short* woutl = wouth + (size_t)VV * HH;

    // zero c0,c1 + all h hi/lo splits (contiguous, 1 MiB total)
    hipMemsetAsync(c0, 0, (size_t)2 * BB * HH * sizeof(float)
                        + (size_t)4 * BB * HH * sizeof(unsigned short), stream);

    const dim3 blk(256);
    const dim3 ggates(NG / 32, KS);
    const dim3 gcell(BB * HH / 256);
    const dim3 glog(VBLK);
    const dim3 gfin(BB);

    // one-time per call: pre-split all constant operands to bf16 hi/lo
    {
        auto gs = [](int n4) { int g = (n4 + 255) / 256; return dim3(g > 2048 ? 2048 : g); };
        split_k<<<gs(NG * DD / 4), blk, 0, stream>>>(Wih0, wih0h, wih0l, NG * DD / 4);
        split_k<<<gs(NG * HH / 4), blk, 0, stream>>>(Whh0, whh0h, whh0l, NG * HH / 4);
        split_k<<<gs(NG * HH / 4), blk, 0, stream>>>(Wih1, wih1h, wih1l, NG * HH / 4);
        split_k<<<gs(NG * HH / 4), blk, 0, stream>>>(Whh1, whh1h, whh1l, NG * HH / 4);
        split_k<<<gs(VV * HH / 4), blk, 0, stream>>>(Wout, wouth, woutl, VV * HH / 4);
        split_k<<<gs(BB * DD / 4), blk, 0, stream>>>(features, xhi, xlo, BB * DD / 4);
    }

    for (int t = 0; t < TT; t++) {
        // layer 0: gates = x@Wih0^T + h0@Whh0^T (fused), then cell
        gates_mfma_k<<<ggates, blk, 0, stream>>>(xhi, xlo, DD, hhi0, hlo0,
                                                 wih0h, wih0l, whh0h, whh0l, part);
        cell_k<<<gcell, blk, 0, stream>>>(part, bih0, bhh0, c0, hhi0, hlo0);
        // layer 1
        gates_mfma_k<<<ggates, blk, 0, stream>>>(hhi0, hlo0, HH, hhi1, hlo1,
                                                 wih1h, wih1l, whh1h, whh1l, part);
        cell_k<<<gcell, blk, 0, stream>>>(part, bih1, bhh1, c1, hhi1, hlo1);
        // output projection (split-bf16 MFMA) + argmax partials
        logits_mfma_k<<<glog, blk, 0, stream>>>(hhi1, hlo1, wouth, woutl, bout, pv, pi);
        // argmax reduce + token write + embedding gather (pre-split)
        final_k<<<gfin, blk, 0, stream>>>(pv, pi, embed, xhi, xlo, out, t);
    }
}

// Round 5
// 2106.786 us; speedup vs baseline: 1.0309x; 1.0309x over previous
//
#include <hip/hip_runtime.h>
#include <math.h>

// SentenceDecoder: B=64, D=512, H=1024, V=32000, L=2, T=32. NG = 4H = 4096.
#define BB 64
#define DD 512
#define HH 1024
#define VV 32000
#define NG 4096
#define TT 32
#define KS 8              // K-split for fused gate GEMM
#define VBLK 500          // V / 64 logits tiles

typedef __bf16 bf16x8 __attribute__((ext_vector_type(8)));
typedef float  f32x4  __attribute__((ext_vector_type(4)));

// split fp32 into bf16 hi + bf16 lo (RN-even both): x ~= hi + lo, err ~2^-17 rel
__device__ __forceinline__ void split_bf16(float x, unsigned short* hi, unsigned short* lo)
{
    unsigned u = __float_as_uint(x);
    unsigned r = (u + 0x7fffu + ((u >> 16) & 1u)) & 0xffff0000u;
    *hi = (unsigned short)(r >> 16);
    float rem = x - __uint_as_float(r);
    unsigned u2 = __float_as_uint(rem);
    unsigned r2 = u2 + 0x7fffu + ((u2 >> 16) & 1u);
    *lo = (unsigned short)(r2 >> 16);
}

// ---------------------------------------------------------------------------
// split_k: fp32 array -> bf16 hi/lo arrays (one-time per call, weights + feat)
// ---------------------------------------------------------------------------
__global__ __launch_bounds__(256)
void split_k(const float* __restrict__ src, unsigned short* __restrict__ hi,
             unsigned short* __restrict__ lo, int n4)
{
    const int stride = gridDim.x * 256;
    for (int i = blockIdx.x * 256 + threadIdx.x; i < n4; i += stride) {
        const float4 v = ((const float4*)src)[i];
        ushort4 h, l;
        split_bf16(v.x, &h.x, &l.x);
        split_bf16(v.y, &h.y, &l.y);
        split_bf16(v.z, &h.z, &l.z);
        split_bf16(v.w, &h.w, &l.w);
        ((ushort4*)hi)[i] = h;
        ((ushort4*)lo)[i] = l;
    }
}

// ---------------------------------------------------------------------------
// gates_mfma_k: fused dual GEMM via split-bf16 MFMA, register-prefetch
// software pipeline (1-deep; only 3-4 chunks per block, prologue-dominated).
//   P[y][b][j] = sum_{k in y-chunk} X[b][k]*Wih[j][k] + H[b][k]*Whh[j][k]
// 64x64 tile per block, 256 thr (4 waves), grid (NG/64, KS) = (64, 8).
// ---------------------------------------------------------------------------
__global__ __launch_bounds__(256)
void gates_mfma_k(const unsigned short* __restrict__ Ahi0, const unsigned short* __restrict__ Alo0,
                  const int K0,
                  const unsigned short* __restrict__ Ahi1, const unsigned short* __restrict__ Alo1,
                  const unsigned short* __restrict__ Wihhi, const unsigned short* __restrict__ Wihlo,
                  const unsigned short* __restrict__ Whhhi, const unsigned short* __restrict__ Whhlo,
                  float* __restrict__ P)
{
    // stride 72 bf16 = 144 B per row: 16B-aligned, only 2-way bank aliasing
    __shared__ unsigned short Ah[64][72], Al[64][72], Wh[64][72], Wl[64][72];

    const int j0   = blockIdx.x * 64;
    const int y    = blockIdx.y;
    const int tid  = threadIdx.x;
    const int wv   = tid >> 6;        // wave id 0..3 -> m rows 16*wv..
    const int lane = tid & 63;
    const int l15  = lane & 15;
    const int q    = lane >> 4;       // quad 0..3
    const int sr   = tid >> 3;        // staging row 0..31
    const int sc   = tid & 7;         // staging 8-bf16 chunk

    f32x4 acc[4] = {{0,0,0,0},{0,0,0,0},{0,0,0,0},{0,0,0,0}};

    // flat chunk schedule: seg0 (X/Wih, K=K0) then seg1 (H/Whh, K=HH),
    // 64-wide chunks within this block's y-slice of each segment.
    const int n0 = K0 >> 9;           // K0/512 chunks in seg0 (kc0/64)
    const int nc = n0 + (HH >> 9);    // + HH/512 chunks in seg1

    uint4 rA0h, rA0l, rA1h, rA1l, rW0h, rW0l, rW1h, rW1l;   // in-flight chunk

#define G_LOAD_CHUNK(cc)                                                        \
    do {                                                                        \
        const int seg_ = ((cc) >= n0);                                          \
        const unsigned short* Ah_ = seg_ ? Ahi1 : Ahi0;                         \
        const unsigned short* Al_ = seg_ ? Alo1 : Alo0;                         \
        const unsigned short* Wh_ = seg_ ? Whhhi : Wihhi;                       \
        const unsigned short* Wl_ = seg_ ? Whhlo : Wihlo;                       \
        const int K_ = seg_ ? HH : K0;                                          \
        const int kb_ = y * (K_ >> 3) + ((cc) - (seg_ ? n0 : 0)) * 64;          \
        const size_t ao_ = (size_t)sr * K_ + kb_ + sc * 8;                      \
        const size_t wo_ = (size_t)(j0 + sr) * K_ + kb_ + sc * 8;               \
        const size_t s32_ = (size_t)32 * K_;                                    \
        rA0h = *(const uint4*)(Ah_ + ao_);                                      \
        rA0l = *(const uint4*)(Al_ + ao_);                                      \
        rA1h = *(const uint4*)(Ah_ + ao_ + s32_);                               \
        rA1l = *(const uint4*)(Al_ + ao_ + s32_);                               \
        rW0h = *(const uint4*)(Wh_ + wo_);                                      \
        rW0l = *(const uint4*)(Wl_ + wo_);                                      \
        rW1h = *(const uint4*)(Wh_ + wo_ + s32_);                               \
        rW1l = *(const uint4*)(Wl_ + wo_ + s32_);                               \
    } while (0)

    G_LOAD_CHUNK(0);
    for (int c = 0; c < nc; ++c) {
        if (c) __syncthreads();            // prev compute done reading LDS
        *(uint4*)&Ah[sr][sc * 8]      = rA0h;
        *(uint4*)&Al[sr][sc * 8]      = rA0l;
        *(uint4*)&Ah[sr + 32][sc * 8] = rA1h;
        *(uint4*)&Al[sr + 32][sc * 8] = rA1l;
        *(uint4*)&Wh[sr][sc * 8]      = rW0h;
        *(uint4*)&Wl[sr][sc * 8]      = rW0l;
        *(uint4*)&Wh[sr + 32][sc * 8] = rW1h;
        *(uint4*)&Wl[sr + 32][sc * 8] = rW1l;
        if (c + 1 < nc) G_LOAD_CHUNK(c + 1);   // issue early: hides under MFMA
        __syncthreads();

#pragma unroll
        for (int ks = 0; ks < 2; ks++) {
            const int ko = ks * 32 + q * 8;
            const bf16x8 ah = *(const bf16x8*)&Ah[16 * wv + l15][ko];
            const bf16x8 al = *(const bf16x8*)&Al[16 * wv + l15][ko];
#pragma unroll
            for (int t = 0; t < 4; t++) {
                const bf16x8 bh = *(const bf16x8*)&Wh[16 * t + l15][ko];
                const bf16x8 bl = *(const bf16x8*)&Wl[16 * t + l15][ko];
                acc[t] = __builtin_amdgcn_mfma_f32_16x16x32_bf16(ah, bl, acc[t], 0, 0, 0);
                acc[t] = __builtin_amdgcn_mfma_f32_16x16x32_bf16(al, bh, acc[t], 0, 0, 0);
                acc[t] = __builtin_amdgcn_mfma_f32_16x16x32_bf16(ah, bh, acc[t], 0, 0, 0);
            }
        }
    }
#undef G_LOAD_CHUNK

    // C/D layout (16x16): col = lane&15, row = q*4 + reg  [m89-verified]
    float* __restrict__ Pout = P + (size_t)y * (BB * NG);
#pragma unroll
    for (int reg = 0; reg < 4; reg++) {
        const int row = 16 * wv + q * 4 + reg;     // batch index
#pragma unroll
        for (int t = 0; t < 4; t++)
            Pout[(size_t)row * NG + j0 + 16 * t + l15] = acc[t][reg];
    }
}

// ---------------------------------------------------------------------------
// cell_k: sum KS partial slices + biases -> gates; LSTM cell; emit bf16 hi/lo
// split of h (the only consumed form of h). c stays fp32.
// ---------------------------------------------------------------------------
__global__ __launch_bounds__(256)
void cell_k(const float* __restrict__ P, const float* __restrict__ bih,
            const float* __restrict__ bhh, float* __restrict__ c,
            unsigned short* __restrict__ hhi, unsigned short* __restrict__ hlo)
{
    const int tid = blockIdx.x * 256 + threadIdx.x;   // B*H threads
    const int b = tid >> 10;
    const int u = tid & (HH - 1);

    float gi = bih[u]          + bhh[u];
    float gf = bih[HH + u]     + bhh[HH + u];
    float gg = bih[2 * HH + u] + bhh[2 * HH + u];
    float go = bih[3 * HH + u] + bhh[3 * HH + u];

#pragma unroll
    for (int s = 0; s < KS; s++) {
        const float* ps = P + (size_t)s * (BB * NG) + (size_t)b * NG;
        gi += ps[u];
        gf += ps[HH + u];
        gg += ps[2 * HH + u];
        go += ps[3 * HH + u];
    }

    const float si = 1.0f / (1.0f + expf(-gi));
    const float sf = 1.0f / (1.0f + expf(-gf));
    const float so = 1.0f / (1.0f + expf(-go));
    const float cn = sf * c[tid] + si * tanhf(gg);
    const float hn = so * tanhf(cn);
    c[tid] = cn;
    split_bf16(hn, &hhi[tid], &hlo[tid]);
}

// ---------------------------------------------------------------------------
// logits_mfma_k: 64x64 logits tile via split-bf16 MFMA with TWO-DEEP
// register-prefetch pipeline (chunk c+1 and c+2 in flight in named register
// sets -> ~2 compute phases (~700+ cyc) of HBM-latency cover per chunk).
// Argmax-partial epilogue. Grid: 500 blocks x 256 thr (4 waves).
// ---------------------------------------------------------------------------
__global__ __launch_bounds__(256)
void logits_mfma_k(const unsigned short* __restrict__ Ahi,
                   const unsigned short* __restrict__ Alo,
                   const unsigned short* __restrict__ Whi,
                   const unsigned short* __restrict__ Wlo,
                   const float* __restrict__ bout,
                   float* __restrict__ pv, int* __restrict__ pi)
{
    __shared__ unsigned short Ah[64][72], Al[64][72], Wh[64][72], Wl[64][72];
    __shared__ float rv[64][16];
    __shared__ int   ri[64][16];

    const int v0   = blockIdx.x * 64;
    const int tid  = threadIdx.x;
    const int wv   = tid >> 6;
    const int lane = tid & 63;
    const int l15  = lane & 15;
    const int q    = lane >> 4;
    const int sr   = tid >> 3;
    const int sc   = tid & 7;

    f32x4 acc[4] = {{0,0,0,0},{0,0,0,0},{0,0,0,0},{0,0,0,0}};

    // two named in-flight chunk register sets (static names: no scratch)
    uint4 pA0h, pA0l, pA1h, pA1l, pW0h, pW0l, pW1h, pW1l;   // set P
    uint4 qA0h, qA0l, qA1h, qA1l, qW0h, qW0l, qW1h, qW1l;   // set Q

#define L_LOAD(kb_, A0h,A0l,A1h,A1l,W0h,W0l,W1h,W1l)                            \
    do {                                                                        \
        const size_t ao_ = (size_t)sr * HH + (kb_) + sc * 8;                    \
        const size_t wo_ = (size_t)(v0 + sr) * HH + (kb_) + sc * 8;             \
        const size_t s32_ = (size_t)32 * HH;                                    \
        A0h = *(const uint4*)(Ahi + ao_);                                       \
        A0l = *(const uint4*)(Alo + ao_);                                       \
        A1h = *(const uint4*)(Ahi + ao_ + s32_);                                \
        A1l = *(const uint4*)(Alo + ao_ + s32_);                                \
        W0h = *(const uint4*)(Whi + wo_);                                       \
        W0l = *(const uint4*)(Wlo + wo_);                                       \
        W1h = *(const uint4*)(Whi + wo_ + s32_);                                \
        W1l = *(const uint4*)(Wlo + wo_ + s32_);                                \
    } while (0)

#define L_STORE(A0h,A0l,A1h,A1l,W0h,W0l,W1h,W1l)                                \
    do {                                                                        \
        *(uint4*)&Ah[sr][sc * 8]      = A0h;                                    \
        *(uint4*)&Al[sr][sc * 8]      = A0l;                                    \
        *(uint4*)&Ah[sr + 32][sc * 8] = A1h;                                    \
        *(uint4*)&Al[sr + 32][sc * 8] = A1l;                                    \
        *(uint4*)&Wh[sr][sc * 8]      = W0h;                                    \
        *(uint4*)&Wl[sr][sc * 8]      = W0l;                                    \
        *(uint4*)&Wh[sr + 32][sc * 8] = W1h;                                    \
        *(uint4*)&Wl[sr + 32][sc * 8] = W1l;                                    \
    } while (0)

#define L_COMPUTE()                                                             \
    do {                                                                        \
        _Pragma("unroll")                                                       \
        for (int ks = 0; ks < 2; ks++) {                                        \
            const int ko = ks * 32 + q * 8;                                     \
            const bf16x8 ah = *(const bf16x8*)&Ah[16 * wv + l15][ko];           \
            const bf16x8 al = *(const bf16x8*)&Al[16 * wv + l15][ko];           \
            _Pragma("unroll")                                                   \
            for (int t = 0; t < 4; t++) {                                       \
                const bf16x8 bh = *(const bf16x8*)&Wh[16 * t + l15][ko];        \
                const bf16x8 bl = *(const bf16x8*)&Wl[16 * t + l15][ko];        \
                acc[t] = __builtin_amdgcn_mfma_f32_16x16x32_bf16(ah, bl, acc[t], 0, 0, 0); \
                acc[t] = __builtin_amdgcn_mfma_f32_16x16x32_bf16(al, bh, acc[t], 0, 0, 0); \
                acc[t] = __builtin_amdgcn_mfma_f32_16x16x32_bf16(ah, bh, acc[t], 0, 0, 0); \
            }                                                                   \
        }                                                                       \
    } while (0)

    // prologue: chunks 0 (P) and 1 (Q) in flight
    L_LOAD(0,  pA0h,pA0l,pA1h,pA1l,pW0h,pW0l,pW1h,pW1l);
    L_LOAD(64, qA0h,qA0l,qA1h,qA1l,qW0h,qW0l,qW1h,qW1l);

    // HH/64 = 16 chunks, unrolled by 2: even chunk from P, odd from Q.
    for (int kb = 0; kb < HH; kb += 128) {
        if (kb) __syncthreads();                 // readers of prev chunk done
        L_STORE(pA0h,pA0l,pA1h,pA1l,pW0h,pW0l,pW1h,pW1l);
        if (kb + 128 < HH)
            L_LOAD(kb + 128, pA0h,pA0l,pA1h,pA1l,pW0h,pW0l,pW1h,pW1l);
        __syncthreads();
        L_COMPUTE();                             // chunk kb

        __syncthreads();                         // readers of chunk kb done
        L_STORE(qA0h,qA0l,qA1h,qA1l,qW0h,qW0l,qW1h,qW1l);
        if (kb + 192 < HH)
            L_LOAD(kb + 192, qA0h,qA0l,qA1h,qA1l,qW0h,qW0l,qW1h,qW1l);
        __syncthreads();
        L_COMPUTE();                             // chunk kb+64
    }
#undef L_LOAD
#undef L_STORE
#undef L_COMPUTE

    // epilogue: +bias, per-lane argmax over its 4 cols per row, then LDS reduce.
    // C/D layout (16x16): col = lane&15, row = q*4 + reg  [m89-verified]
#pragma unroll
    for (int reg = 0; reg < 4; reg++) {
        float best = -INFINITY;
        int bid = 0x7fffffff;
#pragma unroll
        for (int t = 0; t < 4; t++) {
            const int id = v0 + 16 * t + l15;
            const float v = acc[t][reg] + bout[id];
            if (v > best || (v == best && id < bid)) { best = v; bid = id; }
        }
        rv[16 * wv + q * 4 + reg][l15] = best;
        ri[16 * wv + q * 4 + reg][l15] = bid;
    }
    __syncthreads();

    if (tid < 64) {
        float best = -INFINITY;
        int bid = 0x7fffffff;
        for (int k = 0; k < 16; k++) {
            const float v = rv[tid][k];
            const int id = ri[tid][k];
            if (v > best || (v == best && id < bid)) { best = v; bid = id; }
        }
        pv[(size_t)tid * VBLK + blockIdx.x] = best;
        pi[(size_t)tid * VBLK + blockIdx.x] = bid;
    }
}

// ---------------------------------------------------------------------------
// final_k: reduce VBLK argmax partials per row -> token; gather embed row and
// emit it directly as bf16 hi/lo (the only form the gate kernel consumes).
// ---------------------------------------------------------------------------
__global__ __launch_bounds__(256)
void final_k(const float* __restrict__ pv, const int* __restrict__ pi,
             const float* __restrict__ embed, unsigned short* __restrict__ xhi,
             unsigned short* __restrict__ xlo, int* __restrict__ out, int t)
{
    __shared__ float sv[256];
    __shared__ int   si[256];
    const int b = blockIdx.x;
    const int tid = threadIdx.x;

    float best = -INFINITY;
    int bid = 0x7fffffff;
    for (int k = tid; k < VBLK; k += 256) {
        float v = pv[(size_t)b * VBLK + k];
        int id = pi[(size_t)b * VBLK + k];
        if (v > best || (v == best && id < bid)) { best = v; bid = id; }
    }
    sv[tid] = best; si[tid] = bid;
    __syncthreads();
    for (int s = 128; s > 0; s >>= 1) {
        if (tid < s) {
            float v = sv[tid + s]; int id = si[tid + s];
            if (v > sv[tid] || (v == sv[tid] && id < si[tid])) { sv[tid] = v; si[tid] = id; }
        }
        __syncthreads();
    }
    const int pred = si[0];
    if (tid == 0) out[(size_t)b * TT + t] = pred;
    for (int d = tid; d < DD; d += 256) {
        const float v = embed[(size_t)pred * DD + d];
        split_bf16(v, &xhi[(size_t)b * DD + d], &xlo[(size_t)b * DD + d]);
    }
}

// ---------------------------------------------------------------------------
extern "C" void kernel_launch(void* const* d_in, const int* in_sizes, int n_in,
                              void* d_out, int out_size, void* d_ws, size_t ws_size,
                              hipStream_t stream)
{
    const float* features = (const float*)d_in[0];
    const float* embed    = (const float*)d_in[1];
    const float* Wih0     = (const float*)d_in[2];
    const float* Whh0     = (const float*)d_in[3];
    const float* bih0     = (const float*)d_in[4];
    const float* bhh0     = (const float*)d_in[5];
    const float* Wih1     = (const float*)d_in[6];
    const float* Whh1     = (const float*)d_in[7];
    const float* bih1     = (const float*)d_in[8];
    const float* bhh1     = (const float*)d_in[9];
    const float* Wout     = (const float*)d_in[10];
    const float* bout     = (const float*)d_in[11];
    int* out = (int*)d_out;

    // workspace layout (all offsets 16B-aligned)
    float* ws = (float*)d_ws;
    float* c0 = ws;                                            // B*H fp32
    float* c1 = c0 + BB * HH;
    unsigned short* hhi0 = (unsigned short*)(c1 + BB * HH);    // B*H bf16 each
    unsigned short* hlo0 = hhi0 + BB * HH;
    unsigned short* hhi1 = hlo0 + BB * HH;
    unsigned short* hlo1 = hhi1 + BB * HH;
    unsigned short* xhi  = hlo1 + BB * HH;                     // B*D bf16 each
    unsigned short* xlo  = xhi + BB * DD;
    float* part = (float*)(xlo + BB * DD);                     // KS*B*NG fp32
    float* pv   = part + (size_t)KS * BB * NG;                 // B*VBLK
    int*   pi   = (int*)(pv + BB * VBLK);                      // B*VBLK
    unsigned short* wih0h = (unsigned short*)(pi + BB * VBLK); // NG*D each
    unsigned short* wih0l = wih0h + (size_t)NG * DD;
    unsigned short* whh0h = wih0l + (size_t)NG * DD;           // NG*H each
    unsigned short* whh0l = whh0h + (size_t)NG * HH;
    unsigned short* wih1h = whh0l + (size_t)NG * HH;
    unsigned short* wih1l = wih1h + (size_t)NG * HH;
    unsigned short* whh1h = wih1l + (size_t)NG * HH;
    unsigned short* whh1l = whh1h + (size_t)NG * HH;
    unsigned short* wouth = whh1l + (size_t)NG * HH;           // V*H each
    unsigned short* woutl = wouth + (size_t)VV * HH;

    // zero c0,c1 + all h hi/lo splits (contiguous, 1 MiB total)
    hipMemsetAsync(c0, 0, (size_t)2 * BB * HH * sizeof(float)
                        + (size_t)4 * BB * HH * sizeof(unsigned short), stream);

    const dim3 blk(256);
    const dim3 ggates(NG / 64, KS);
    const dim3 gcell(BB * HH / 256);
    const dim3 glog(VBLK);
    const dim3 gfin(BB);

    // one-time per call: pre-split all constant operands to bf16 hi/lo
    {
        auto gs = [](int n4) { int g = (n4 + 255) / 256; return dim3(g > 2048 ? 2048 : g); };
        split_k<<<gs(NG * DD / 4), blk, 0, stream>>>(Wih0, wih0h, wih0l, NG * DD / 4);
        split_k<<<gs(NG * HH / 4), blk, 0, stream>>>(Whh0, whh0h, whh0l, NG * HH / 4);
        split_k<<<gs(NG * HH / 4), blk, 0, stream>>>(Wih1, wih1h, wih1l, NG * HH / 4);
        split_k<<<gs(NG * HH / 4), blk, 0, stream>>>(Whh1, whh1h, whh1l, NG * HH / 4);
        split_k<<<gs(VV * HH / 4), blk, 0, stream>>>(Wout, wouth, woutl, VV * HH / 4);
        split_k<<<gs(BB * DD / 4), blk, 0, stream>>>(features, xhi, xlo, BB * DD / 4);
    }

    for (int t = 0; t < TT; t++) {
        // layer 0: gates = x@Wih0^T + h0@Whh0^T (fused), then cell
        gates_mfma_k<<<ggates, blk, 0, stream>>>(xhi, xlo, DD, hhi0, hlo0,
                                                 wih0h, wih0l, whh0h, whh0l, part);
        cell_k<<<gcell, blk, 0, stream>>>(part, bih0, bhh0, c0, hhi0, hlo0);
        // layer 1
        gates_mfma_k<<<ggates, blk, 0, stream>>>(hhi0, hlo0, HH, hhi1, hlo1,
                                                 wih1h, wih1l, whh1h, whh1l, part);
        cell_k<<<gcell, blk, 0, stream>>>(part, bih1, bhh1, c1, hhi1, hlo1);
        // output projection (split-bf16 MFMA) + argmax partials
        logits_mfma_k<<<glog, blk, 0, stream>>>(hhi1, hlo1, wouth, woutl, bout, pv, pi);
        // argmax reduce + token write + embedding gather (pre-split)
        final_k<<<gfin, blk, 0, stream>>>(pv, pi, embed, xhi, xlo, out, t);
    }
}